// Round 4
// baseline (114511.914 us; speedup 1.0000x reference)
//
#include <hip/hip_runtime.h>
#include <math.h>

#define T_STEPS 16384
#define IN 512
#define HID 1024
#define NC 512
#define NWG 256
#define TPB 256
#define TB 32           // t-rows per block in dense kernel
typedef unsigned long long ull;

#define LIDX(j) ((j) + ((j) >> 5))      // LDS pad: +1 slot per 32 -> ~4-way banks
#define LSZ (HID + (HID >> 5))          // 1056

__device__ __forceinline__ float sigmoidf_(float x) { return 1.f / (1.f + expf(-x)); }

// ---------------- Kernel 0: seed epoch-tagged h buffer ----------------
// bufp[p][j] = {epoch:u32 | h:f32}. h_t carries epoch t+1 (h0 -> epoch 1, parity 0).
// ws is NOT re-poisoned between timed replays -> must reset both parities.
__global__ void init_k(const float* __restrict__ h0, ull* __restrict__ bufp)
{
    const int j = threadIdx.x;  // 1024 threads, 1 block
    bufp[j]       = (1ull << 32) | (ull)__float_as_uint(h0[j]);
    bufp[HID + j] = 0ull;
}

// ---------------- Kernel 1: persistent LSTM recurrence ----------------
// 256 WGs x 256 threads (4 waves), 1 WG/CU. Wave wv of WG wg owns h elem
// j = wg*4+wv and its 4 gate rows; weights pinned in VGPRs via asm keep-alive.
// NO __syncthreads in the step loop: wave wv stages global quarter wv into an
// epoch-tagged LDS table; consumers spin on LDS epochs per 4-elem chunk.
__global__ __launch_bounds__(TPB, 1) void lstm_rec(
    const float* __restrict__ X,     // [T, IN]
    const float* __restrict__ c0,    // [HID]
    const float* __restrict__ W_ih,  // [4H, IN]
    const float* __restrict__ W_hh,  // [4H, HID]
    const float* __restrict__ b_ih,  // [4H]
    const float* __restrict__ b_hh,  // [4H]
    float* __restrict__ h_all,       // ws [T, HID]
    ull* __restrict__ bufp)          // ws [2][HID] epoch|h
{
    __shared__ ull sh[2][LSZ];       // ~16.9 KB epoch-tagged h (2 parities)

    const int tid  = threadIdx.x;
    const int wg   = blockIdx.x;
    const int lane = tid & 63;
    const int wv   = tid >> 6;
    const int j    = wg * 4 + wv;    // owned h element

    for (int i = tid; i < LSZ; i += TPB) { sh[0][i] = 0ull; sh[1][i] = 0ull; }

    // --- weights for the 4 gate rows of elem j: 96 scalars, truly in VGPRs ---
    float w[4][24];
    float bias[4];
    #pragma unroll
    for (int q = 0; q < 4; ++q) {
        const int row = q * HID + j;
        #pragma unroll
        for (int c = 0; c < 6; ++c) {
            const int k = lane * 4 + c * 256;
            const float4 t4 = (k < IN)
                ? *(const float4*)&W_ih[(size_t)row * IN + k]
                : *(const float4*)&W_hh[(size_t)row * HID + (k - IN)];
            w[q][c * 4 + 0] = t4.x; w[q][c * 4 + 1] = t4.y;
            w[q][c * 4 + 2] = t4.z; w[q][c * 4 + 3] = t4.w;
        }
        bias[q] = b_ih[row] + b_hh[row];
    }
    #pragma unroll
    for (int q = 0; q < 4; ++q) {
        #pragma unroll
        for (int c = 0; c < 6; ++c) {
            asm volatile("" : "+v"(w[q][c*4+0]), "+v"(w[q][c*4+1]),
                             "+v"(w[q][c*4+2]), "+v"(w[q][c*4+3]));
        }
    }

    float c_state = c0[j];           // redundant on all lanes (consistent)
    bool dead = false;
    __syncthreads();                 // LDS zero-init visible (one-time)

    const int sbase = wv * 256 + lane * 4;   // this lane's staging slice

    for (int t = 0; t < T_STEPS; ++t) {
        const int p = t & 1;
        const unsigned want = (unsigned)(t + 1);

        // x slice to registers (overlaps everything below)
        const float* xr = X + (size_t)t * IN;
        const float4 x0 = *(const float4*)&xr[lane * 4];
        const float4 x1 = *(const float4*)&xr[lane * 4 + 256];

        // ---- stage global quarter wv -> LDS (per-lane granular poll) ----
        ull* src = bufp + (size_t)p * HID;
        ull g0, g1, g2, g3;
        unsigned sp = 0;
        for (;;) {
            g0 = __hip_atomic_load(&src[sbase + 0], __ATOMIC_RELAXED, __HIP_MEMORY_SCOPE_AGENT);
            g1 = __hip_atomic_load(&src[sbase + 1], __ATOMIC_RELAXED, __HIP_MEMORY_SCOPE_AGENT);
            g2 = __hip_atomic_load(&src[sbase + 2], __ATOMIC_RELAXED, __HIP_MEMORY_SCOPE_AGENT);
            g3 = __hip_atomic_load(&src[sbase + 3], __ATOMIC_RELAXED, __HIP_MEMORY_SCOPE_AGENT);
            unsigned em = min(min((unsigned)(g0 >> 32), (unsigned)(g1 >> 32)),
                              min((unsigned)(g2 >> 32), (unsigned)(g3 >> 32)));
            if (em >= want || dead) break;
            if (++sp > 4000000u) { dead = true; break; }
        }
        sh[p][LIDX(sbase + 0)] = g0;
        sh[p][LIDX(sbase + 1)] = g1;
        sh[p][LIDX(sbase + 2)] = g2;
        sh[p][LIDX(sbase + 3)] = g3;

        // ---- x-part FMAs while h chunks land ----
        float acc[4];
        #pragma unroll
        for (int q = 0; q < 4; ++q) {
            acc[q] = w[q][0]*x0.x + w[q][1]*x0.y + w[q][2]*x0.z + w[q][3]*x0.w
                   + w[q][4]*x1.x + w[q][5]*x1.y + w[q][6]*x1.z + w[q][7]*x1.w;
        }

        // ---- per-chunk LDS epoch spin + FMA (no barriers) ----
        #pragma unroll
        for (int c = 0; c < 4; ++c) {
            const int e = lane * 4 + c * 256;
            volatile const ull* vs = &sh[p][0];
            ull u0, u1, u2, u3;
            unsigned sp2 = 0;
            for (;;) {
                u0 = vs[LIDX(e + 0)]; u1 = vs[LIDX(e + 1)];
                u2 = vs[LIDX(e + 2)]; u3 = vs[LIDX(e + 3)];
                unsigned em = min(min((unsigned)(u0 >> 32), (unsigned)(u1 >> 32)),
                                  min((unsigned)(u2 >> 32), (unsigned)(u3 >> 32)));
                if (em >= want || dead) break;
                if (++sp2 > 4000000u) { dead = true; break; }
            }
            const float h0v = __uint_as_float((unsigned)u0);
            const float h1v = __uint_as_float((unsigned)u1);
            const float h2v = __uint_as_float((unsigned)u2);
            const float h3v = __uint_as_float((unsigned)u3);
            #pragma unroll
            for (int q = 0; q < 4; ++q) {
                acc[q] += w[q][8 + c*4 + 0] * h0v + w[q][8 + c*4 + 1] * h1v
                        + w[q][8 + c*4 + 2] * h2v + w[q][8 + c*4 + 3] * h3v;
            }
        }

        // butterfly reduce (4 independent chains interleave)
        #pragma unroll
        for (int q = 0; q < 4; ++q) {
            float s = acc[q];
            #pragma unroll
            for (int off = 32; off; off >>= 1) s += __shfl_xor(s, off);
            acc[q] = s;
        }

        // activations redundantly on all lanes (same result, no divergence stall)
        const float iv = sigmoidf_(acc[0] + bias[0]);
        const float fv = sigmoidf_(acc[1] + bias[1]);
        const float gv = tanhf   (acc[2] + bias[2]);
        const float ov = sigmoidf_(acc[3] + bias[3]);
        c_state = fv * c_state + iv * gv;
        const float h = ov * tanhf(c_state);

        if (lane == 0) {
            // publish FIRST (critical path), h_all after
            __hip_atomic_store(&bufp[(size_t)(p ^ 1) * HID + j],
                ((ull)(unsigned)(t + 2) << 32) | (ull)__float_as_uint(h),
                __ATOMIC_RELAXED, __HIP_MEMORY_SCOPE_AGENT);
            h_all[(size_t)t * HID + j] = h;
        }
    }
}

// ---------------- Kernel 2: out_t = softmax_C(h_t @ Wd^T + bd) ----------------
// 512 blocks x 256 threads, 32 t-rows/block: Wd re-read traffic 4GB -> 1GB.
__global__ __launch_bounds__(256, 2) void dense_softmax(
    const float* __restrict__ h_all, const float* __restrict__ Wd,
    const float* __restrict__ bd, float* __restrict__ P)
{
    __shared__ float buf[TB * NC];    // 64KB union: hs[TB][128] then ls[TB][NC]
    const int tid = threadIdx.x;
    const int t0  = blockIdx.x * TB;
    const int c0 = tid, c1 = tid + 256;

    float acc0[TB], acc1[TB];
    #pragma unroll
    for (int r = 0; r < TB; ++r) { acc0[r] = 0.f; acc1[r] = 0.f; }

    const float4* wrow0 = (const float4*)&Wd[(size_t)c0 * HID];
    const float4* wrow1 = (const float4*)&Wd[(size_t)c1 * HID];

    for (int kc = 0; kc < HID / 128; ++kc) {
        // stage h chunk [TB][128]
        #pragma unroll
        for (int i = 0; i < 4; ++i) {
            const int idx4 = tid + i * 256;          // float4 index into [TB*128/4]
            const int r = idx4 >> 5, kk = (idx4 & 31) * 4;
            *(float4*)&buf[r * 128 + kk] =
                *(const float4*)&h_all[(size_t)(t0 + r) * HID + kc * 128 + kk];
        }
        __syncthreads();
        #pragma unroll 8
        for (int k4 = 0; k4 < 32; ++k4) {
            const float4 a = wrow0[kc * 32 + k4];
            const float4 b = wrow1[kc * 32 + k4];
            #pragma unroll
            for (int r = 0; r < TB; ++r) {
                const float4 h4 = *(const float4*)&buf[r * 128 + k4 * 4];  // broadcast
                acc0[r] += a.x*h4.x + a.y*h4.y + a.z*h4.z + a.w*h4.w;
                acc1[r] += b.x*h4.x + b.y*h4.y + b.z*h4.z + b.w*h4.w;
            }
        }
        __syncthreads();   // hs consumed; safe to overwrite (or reuse as ls)
    }

    const float bb0 = bd[c0], bb1 = bd[c1];
    #pragma unroll
    for (int r = 0; r < TB; ++r) {
        buf[r * NC + c0] = acc0[r] + bb0;   // ls phase (union with hs region)
        buf[r * NC + c1] = acc1[r] + bb1;
    }
    __syncthreads();

    const int lane = tid & 63, wvv = tid >> 6;
    for (int rr = 0; rr < 8; ++rr) {
        const int r = wvv * 8 + rr;
        float vals[8];
        float m = -1e30f;
        #pragma unroll
        for (int jx = 0; jx < 8; ++jx) { vals[jx] = buf[r * NC + lane + 64 * jx]; m = fmaxf(m, vals[jx]); }
        #pragma unroll
        for (int off = 32; off; off >>= 1) m = fmaxf(m, __shfl_xor(m, off));
        float s = 0.f;
        #pragma unroll
        for (int jx = 0; jx < 8; ++jx) { vals[jx] = expf(vals[jx] - m); s += vals[jx]; }
        #pragma unroll
        for (int off = 32; off; off >>= 1) s += __shfl_xor(s, off);
        const float inv = 1.f / s;
        #pragma unroll
        for (int jx = 0; jx < 8; ++jx)
            P[(size_t)(t0 + r) * NC + lane + 64 * jx] = vals[jx] * inv;
    }
}

// ---------------- Kernel 3a: colsum[c] = sum_t exp(P[t][c]) ----------------
__global__ __launch_bounds__(256) void colsum_k(const float* __restrict__ P, float* __restrict__ cs)
{
    const int tid = threadIdx.x;
    const int c  = blockIdx.x * 16 + (tid & 15);
    const int tr = tid >> 4;
    float s = 0.f;
    #pragma unroll 8
    for (int t = tr; t < T_STEPS; t += 16) s += expf(P[(size_t)t * NC + c]);
    __shared__ float red[256];
    red[tid] = s; __syncthreads();
    for (int off = 128; off >= 16; off >>= 1) {
        if (tid < off) red[tid] += red[tid + off];
        __syncthreads();
    }
    if (tid < 16) cs[blockIdx.x * 16 + tid] = red[tid];
}

// ---------------- Kernel 3b: out = exp(P) / colsum ----------------
__global__ __launch_bounds__(256) void norm_k(float* P, const float* __restrict__ cs)
{
    size_t i = (size_t)blockIdx.x * 256 + threadIdx.x;
    const size_t n = (size_t)T_STEPS * NC;
    const size_t stride = (size_t)gridDim.x * 256;
    for (; i < n; i += stride) P[i] = expf(P[i]) / cs[i & (NC - 1)];
}

extern "C" void kernel_launch(void* const* d_in, const int* in_sizes, int n_in,
                              void* d_out, int out_size, void* d_ws, size_t ws_size,
                              hipStream_t stream) {
    const float* X    = (const float*)d_in[0];
    const float* h0   = (const float*)d_in[1];
    const float* c0   = (const float*)d_in[2];
    const float* W_ih = (const float*)d_in[3];
    const float* W_hh = (const float*)d_in[4];
    const float* b_ih = (const float*)d_in[5];
    const float* b_hh = (const float*)d_in[6];
    const float* Wd   = (const float*)d_in[7];
    const float* bd   = (const float*)d_in[8];
    float* out = (float*)d_out;

    char* ws = (char*)d_ws;
    ull*   bufp  = (ull*)ws;                     // [2][HID] epoch|h
    float* cs    = (float*)(ws + 16384);         // [NC]
    float* h_all = (float*)(ws + 32768);         // [T, HID]

    init_k<<<1, HID, 0, stream>>>(h0, bufp);
    lstm_rec<<<NWG, TPB, 0, stream>>>(X, c0, W_ih, W_hh, b_ih, b_hh, h_all, bufp);
    dense_softmax<<<T_STEPS / TB, 256, 0, stream>>>(h_all, Wd, bd, out);
    colsum_k<<<NC / 16, 256, 0, stream>>>(out, cs);
    norm_k<<<2048, 256, 0, stream>>>(out, cs);
}